// Round 9
// baseline (330.313 us; speedup 1.0000x reference)
//
#include <hip/hip_runtime.h>
#include <math.h>

#define BB 2
#define TT 8
#define NN 512
#define HH 64
#define NC 10

typedef unsigned char uchar;

__device__ __forceinline__ float elu1(float v){ return v > 0.f ? v : expm1f(v); }
__device__ __forceinline__ float sigm(float v){ return 1.f/(1.f+expf(-v)); }

// ---------------- K0: masks M0/M1; zero hseq+done; AB; GRU weight transposes ---
__global__ __launch_bounds__(256) void k_mask(
    const float* __restrict__ dW, const float* __restrict__ sadj,
    uchar* __restrict__ M0, uchar* __restrict__ M1,
    float* __restrict__ hseq, unsigned* __restrict__ done,
    const float* __restrict__ att1, const float* __restrict__ Wr1,
    const float* __restrict__ Wl1, float* __restrict__ AB,
    const float* __restrict__ Whh0, const float* __restrict__ Wih1,
    const float* __restrict__ Whh1, float4* __restrict__ WT4)
{
    __shared__ float tr[64][65];
    int bx = blockIdx.x, by = blockIdx.y;
    int tid = threadIdx.x;
    if (blockIdx.z == 1){
        int idx = (by*8 + bx)*256 + tid;
        if (idx < 3*4096){
            int m = idx >> 12, r = idx & 4095;
            int gg = r >> 6, k = r & 63;
            const float* W = (m == 0) ? Whh0 : (m == 1) ? Wih1 : Whh1;
            float4 o;
            o.x = W[k*192 + gg];
            o.y = W[k*192 + 64 + gg];
            o.z = W[k*192 + 128 + gg];
            o.w = 0.f;
            WT4[idx] = o;
        }
        return;
    }
    int i0 = by*64, j0 = bx*64;
    #pragma unroll
    for (int q = 0; q < 4; ++q){
        int r = (tid >> 4) + 16*q, c4 = tid & 15;
        float4 v = *(const float4*)&dW[(size_t)(j0+r)*NN + i0 + 4*c4];
        tr[r][4*c4+0] = v.x; tr[r][4*c4+1] = v.y;
        tr[r][4*c4+2] = v.z; tr[r][4*c4+3] = v.w;
    }
    __syncthreads();
    #pragma unroll
    for (int q = 0; q < 4; ++q){
        int row = (tid >> 4) + 16*q, c4 = tid & 15;
        int i = i0 + row, j = j0 + 4*c4;
        float4 d  = *(const float4*)&dW[(size_t)i*NN + j];
        float4 sa = *(const float4*)&sadj[(size_t)i*NN + j];
        uchar4 m0, m1;
        float dd0 = d.x + tr[4*c4+0][row];
        float dd1 = d.y + tr[4*c4+1][row];
        float dd2 = d.z + tr[4*c4+2][row];
        float dd3 = d.w + tr[4*c4+3][row];
        m0.x = (sa.x > 0.f) || (i == j+0);
        m0.y = (sa.y > 0.f) || (i == j+1);
        m0.z = (sa.z > 0.f) || (i == j+2);
        m0.w = (sa.w > 0.f) || (i == j+3);
        m1.x = m0.x || (dd0 > 0.f);
        m1.y = m0.y || (dd1 > 0.f);
        m1.z = m0.z || (dd2 > 0.f);
        m1.w = m0.w || (dd3 > 0.f);
        *(uchar4*)&M0[(size_t)i*NN + j] = m0;
        *(uchar4*)&M1[(size_t)i*NN + j] = m1;
    }
    int flat = (by*8 + bx)*256 + tid;
    if (flat < BB*TT*HH) hseq[flat] = 0.f;
    else if (flat == BB*TT*HH) done[0] = 0u;
    if (bx == 0 && by == 0 && tid < 8){
        int h = tid & 3;
        const float* W = (tid < 4) ? Wr1 : Wl1;
        float s = 0.f;
        for (int c = 0; c < 16; ++c) s += att1[h*16+c]*W[h*16+c];
        AB[tid] = s;
    }
}

// ---------------- K1: GAT1 fused with lin2 (h1 stays in LDS) -------------------
__global__ __launch_bounds__(256) void k_gat1f(
    const float* __restrict__ x_seq, const uchar* __restrict__ M0,
    const uchar* __restrict__ M1,
    const float* __restrict__ Wl, const float* __restrict__ Wr,
    const float* __restrict__ att, const float* __restrict__ bias,
    const float* __restrict__ AB,
    const float* __restrict__ Wl2, const float* __restrict__ Wr2,
    const float* __restrict__ att2,
    float* __restrict__ xl2, float* __restrict__ xr2,
    float* __restrict__ ui, float* __restrict__ vj)
{
    __shared__ float x_s[NN];
    __shared__ float S_s[4][4];
    __shared__ float h_s[4][HH];
    __shared__ float Wl2_s[64*64];
    __shared__ float Wr2_s[64*64];
    int bt = blockIdx.y; int t = bt % TT;
    int i0 = blockIdx.x * 4;
    int tid = threadIdx.x;
    int il = tid >> 6, jl = tid & 63;
    int i = i0 + il;
    const uchar* M = t ? M1 : M0;
    ((float2*)x_s)[tid] = ((const float2*)(x_seq + bt*NN))[tid];
    #pragma unroll
    for (int q = 0; q < 4; ++q){
        int idx = q*256 + tid;
        ((float4*)Wl2_s)[idx] = ((const float4*)Wl2)[idx];
        ((float4*)Wr2_s)[idx] = ((const float4*)Wr2)[idx];
    }
    __syncthreads();
    float xi = x_s[i];
    const uchar* Mrow = M + (size_t)i*NN;
    float xj[8], msk[8];
    #pragma unroll
    for (int jj = 0; jj < 8; ++jj){
        int j = jj*64 + jl;
        xj[jj] = x_s[j];
        msk[jj] = Mrow[j] ? 1.f : 0.f;
    }
    float sw[4] = {0,0,0,0}, swx[4] = {0,0,0,0};
    for (int h = 0; h < 4; ++h){
        float acc[8] = {0,0,0,0,0,0,0,0};
        #pragma unroll
        for (int c = 0; c < 16; ++c){
            int hc = h*16 + c;
            float wl = Wl[hc];
            float q  = 0.4f * att[hc];
            float pr = xi * Wr[hc];
            #pragma unroll
            for (int jj = 0; jj < 8; ++jj){
                float s = fmaf(xj[jj], wl, pr);
                acc[jj] = fmaf(q, fabsf(s), acc[jj]);
            }
        }
        float lin = 0.6f * xi * AB[h];
        float al6 = 0.6f * AB[4+h];
        #pragma unroll
        for (int jj = 0; jj < 8; ++jj){
            float e = acc[jj] + fmaf(al6, xj[jj], lin);
            float w = msk[jj] * __expf(e);
            sw[h] += w;
            swx[h] = fmaf(w, xj[jj], swx[h]);
        }
    }
    #pragma unroll
    for (int off = 32; off; off >>= 1){
        #pragma unroll
        for (int h = 0; h < 4; ++h){
            sw[h]  += __shfl_down(sw[h],  off);
            swx[h] += __shfl_down(swx[h], off);
        }
    }
    if (jl == 0){
        #pragma unroll
        for (int h = 0; h < 4; ++h) S_s[il][h] = swx[h] / sw[h];
    }
    __syncthreads();
    {
        int hc = tid & 63, row = tid >> 6;
        float v = S_s[row][hc >> 4] * Wl[hc] + bias[hc];
        h_s[row][hc] = elu1(v);
    }
    __syncthreads();
    {
        int c = tid & 63, row = tid >> 6;
        float al = 0.f, ar = 0.f;
        #pragma unroll 8
        for (int k = 0; k < 64; ++k){
            float hv = h_s[row][k];
            al = fmaf(hv, Wl2_s[k*64 + c], al);
            ar = fmaf(hv, Wr2_s[k*64 + c], ar);
        }
        size_t ridx = (size_t)(bt*NN + i0 + row);
        xl2[ridx*HH + c] = al;
        xr2[ridx*HH + c] = ar;
        float a2 = att2[c];
        float pu = a2 * ar, pv = a2 * al;
        #pragma unroll
        for (int off = 32; off; off >>= 1){
            pu += __shfl_down(pu, off);
            pv += __shfl_down(pv, off);
        }
        if (c == 0){ ui[ridx] = pu; vj[ridx] = pv; }
    }
}

// ---------------- K2: GAT2 flash (8-row tiles) + GRU/head tail in last block ---
// grid (64, 16), 256 threads = 8 ti x 32 tj. XOR swizzle on xlR columns.
#define SWZ(c4, j) ((c4) ^ (((j) >> 3) & 3))
__global__ __launch_bounds__(256) void k_flash2(
    const float* __restrict__ xl2, const float* __restrict__ xr2,
    const uchar* __restrict__ M0, const uchar* __restrict__ M1,
    const float* __restrict__ att, const float* __restrict__ bias,
    const float* __restrict__ ui, const float* __restrict__ vj,
    float* __restrict__ hseq, unsigned* __restrict__ done,
    const float* __restrict__ Wih0, const float* __restrict__ bih0,
    const float4* __restrict__ WT4, const float* __restrict__ bhh0,
    const float* __restrict__ bih1, const float* __restrict__ bhh1,
    const float* __restrict__ lamp, const float* __restrict__ attn_W,
    const float* __restrict__ attn_b, const float* __restrict__ W1,
    const float* __restrict__ b1, const float* __restrict__ ln_g,
    const float* __restrict__ ln_b, const float* __restrict__ W2,
    const float* __restrict__ b2, float* __restrict__ out)
{
    __shared__ __align__(16) float S[5632];
    __shared__ unsigned isLast;
    float* xrR  = S;              // [8][68]   544
    float* xlR  = S + 544;        // [64][68]  4352
    float* w_s  = S + 4896;       // [8][68]   544
    float* vj_s = S + 5440;       // 64
    float* Zl   = S + 5504;       // 8
    float* msum = S + 5512;       // 64
    int bt = blockIdx.y, it = blockIdx.x;
    int i0 = it*8, t = bt % TT, base = bt*NN;
    const uchar* M = t ? M1 : M0;
    int tid = threadIdx.x;
    int ti = tid >> 5, tj = tid & 31;
    int tc = tj & 15, jh = tj >> 4;
    if (tid < 128){
        int r = tid >> 4, c4 = tid & 15;
        *(float4*)&xrR[r*68 + 4*c4] = *(const float4*)&xr2[(size_t)(base+i0+r)*HH + 4*c4];
    }
    if (tid < 64) msum[tid] = 0.f;
    float u = ui[base + i0 + ti];
    float zacc = 0.f;
    float4 acc = {0,0,0,0};
    int sa = (tj >> 3) & 3;       // swizzle key for row tj AND tj+32 (same)
    for (int jt = 0; jt < 8; ++jt){
        int j0 = jt*64;
        #pragma unroll
        for (int q = 0; q < 4; ++q){
            int idx = q*256 + tid;
            int r = idx >> 4, c4 = idx & 15;
            *(float4*)&xlR[r*68 + 4*SWZ(c4, r)] =
                *(const float4*)&xl2[(size_t)(base+j0+r)*HH + 4*c4];
        }
        if (tid < 64) vj_s[tid] = vj[base + j0 + tid];
        __syncthreads();
        int ja = tj, jb = tj + 32;
        float e0a = 0.6f*(u + vj_s[ja]), e0b = 0.f;
        float e1a = 0.6f*(u + vj_s[jb]), e1b = 0.f;
        #pragma unroll
        for (int cq = 0; cq < 16; ++cq){
            float4 qa = ((const float4*)att)[cq];
            qa.x *= 0.4f; qa.y *= 0.4f; qa.z *= 0.4f; qa.w *= 0.4f;
            float4 a4 = *(const float4*)&xrR[ti*68 + 4*cq];
            float4 b0 = *(const float4*)&xlR[ja*68 + 4*(cq ^ sa)];
            float4 b1 = *(const float4*)&xlR[jb*68 + 4*(cq ^ sa)];
            e0a = fmaf(qa.x, fabsf(a4.x + b0.x), e0a);
            e0b = fmaf(qa.y, fabsf(a4.y + b0.y), e0b);
            e0a = fmaf(qa.z, fabsf(a4.z + b0.z), e0a);
            e0b = fmaf(qa.w, fabsf(a4.w + b0.w), e0b);
            e1a = fmaf(qa.x, fabsf(a4.x + b1.x), e1a);
            e1b = fmaf(qa.y, fabsf(a4.y + b1.y), e1b);
            e1a = fmaf(qa.z, fabsf(a4.z + b1.z), e1a);
            e1b = fmaf(qa.w, fabsf(a4.w + b1.w), e1b);
        }
        const uchar* Mrow = M + (size_t)(i0+ti)*NN + j0;
        float w0 = Mrow[ja] ? __expf(e0a + e0b) : 0.f;
        float w1 = Mrow[jb] ? __expf(e1a + e1b) : 0.f;
        w_s[ti*68 + ja] = w0;
        w_s[ti*68 + jb] = w1;
        float zp = w0 + w1;
        zp += __shfl_down(zp, 16, 32);
        zp += __shfl_down(zp, 8, 32);
        zp += __shfl_down(zp, 4, 32);
        zp += __shfl_down(zp, 2, 32);
        zp += __shfl_down(zp, 1, 32);
        if (tj == 0) zacc += zp;
        __syncthreads();
        // agg: thread (ti, tc, jh) -> row ti, cols 4tc..4tc+3, j in [32jh, 32jh+32)
        #pragma unroll 8
        for (int jj = 0; jj < 32; ++jj){
            int j = jh*32 + jj;
            float w = w_s[ti*68 + j];
            float4 x4 = *(const float4*)&xlR[j*68 + 4*SWZ(tc, j)];
            acc.x = fmaf(w, x4.x, acc.x);
            acc.y = fmaf(w, x4.y, acc.y);
            acc.z = fmaf(w, x4.z, acc.z);
            acc.w = fmaf(w, x4.w, acc.w);
        }
        __syncthreads();
    }
    acc.x += __shfl_down(acc.x, 16, 32);
    acc.y += __shfl_down(acc.y, 16, 32);
    acc.z += __shfl_down(acc.z, 16, 32);
    acc.w += __shfl_down(acc.w, 16, 32);
    if (tj == 0) Zl[ti] = zacc;
    __syncthreads();
    if (jh == 0){
        float rz = 1.f / Zl[ti];
        float4 b4 = ((const float4*)bias)[tc];
        float4 h;
        h.x = elu1(acc.x*rz + b4.x);
        h.y = elu1(acc.y*rz + b4.y);
        h.z = elu1(acc.z*rz + b4.z);
        h.w = elu1(acc.w*rz + b4.w);
        atomicAdd(&msum[4*tc+0], h.x);
        atomicAdd(&msum[4*tc+1], h.y);
        atomicAdd(&msum[4*tc+2], h.z);
        atomicAdd(&msum[4*tc+3], h.w);
    }
    __syncthreads();
    if (tid < 64) atomicAdd(&hseq[bt*HH + tid], msum[tid]*(1.f/(float)NN));
    // ---- last-block detection ----
    if (tid == 0){
        __threadfence();
        unsigned old = __hip_atomic_fetch_add(done, 1u, __ATOMIC_ACQ_REL, __HIP_MEMORY_SCOPE_AGENT);
        isLast = (old == 64u*16u - 1u) ? 1u : 0u;
        if (isLast) __threadfence();
    }
    __syncthreads();
    if (!isLast) return;
    // ================= tail: hseq -> GRU x2 -> head (one block, 256 thr) =======
    float* hs   = S;              // 1024
    float* gi_s = S + 1024;       // 3072
    float* y_s  = S + 4096;       // 1024
    float* sc_s = S + 5120;       // 16
    float* at_s = S + 5136;       // 16
    float* fin_s= S + 5152;       // 128
    float* z_s  = S + 5280;       // 128
    float* g_s  = S + 5408;       // 128
    float* mu_s = S + 5536;       // 2
    float* iv_s = S + 5538;       // 2
    __syncthreads();
    for (int o = tid; o < BB*TT*HH; o += 256)
        hs[o] = __hip_atomic_load(&hseq[o], __ATOMIC_RELAXED, __HIP_MEMORY_SCOPE_AGENT);
    __syncthreads();
    for (int o = tid; o < BB*TT*192; o += 256){
        int b = o / 192, g = o % 192;
        float a = bih0[g];
        #pragma unroll 8
        for (int k = 0; k < HH; ++k)
            a = fmaf(hs[b*HH + k], Wih0[k*192 + g], a);
        gi_s[o] = a;
    }
    __syncthreads();
    int wave = tid >> 6, lane = tid & 63;
    if (wave < 2){
        int b = wave;
        float y[TT], g1r[TT], g1z[TT], g1n[TT];
        {
            float bhr = bhh0[lane], bhz = bhh0[64+lane], bhn = bhh0[128+lane];
            float h = 0.f;
            for (int tt = 0; tt < TT; ++tt){
                float ghr = bhr, ghz = bhz, ghn = bhn;
                #pragma unroll
                for (int k = 0; k < 64; ++k){
                    float4 w4 = WT4[lane*64 + k];
                    float hk = __shfl(h, k);
                    ghr = fmaf(w4.x, hk, ghr);
                    ghz = fmaf(w4.y, hk, ghz);
                    ghn = fmaf(w4.z, hk, ghn);
                }
                const float* gi = &gi_s[(b*TT + tt)*192];
                float r = sigm(gi[lane] + ghr);
                float z = sigm(gi[64+lane] + ghz);
                float n = tanhf(gi[128+lane] + r*ghn);
                h = (1.f - z)*n + z*h;
                y[tt] = h;
            }
        }
        {
            float bi1r = bih1[lane], bi1z = bih1[64+lane], bi1n = bih1[128+lane];
            #pragma unroll
            for (int tt = 0; tt < TT; ++tt){ g1r[tt] = bi1r; g1z[tt] = bi1z; g1n[tt] = bi1n; }
            #pragma unroll 8
            for (int k = 0; k < 64; ++k){
                float4 w4 = WT4[4096 + lane*64 + k];
                #pragma unroll
                for (int tt = 0; tt < TT; ++tt){
                    float yk = __shfl(y[tt], k);
                    g1r[tt] = fmaf(w4.x, yk, g1r[tt]);
                    g1z[tt] = fmaf(w4.y, yk, g1z[tt]);
                    g1n[tt] = fmaf(w4.z, yk, g1n[tt]);
                }
            }
        }
        {
            float bhr = bhh1[lane], bhz = bhh1[64+lane], bhn = bhh1[128+lane];
            float h = 0.f;
            for (int tt = 0; tt < TT; ++tt){
                float ghr = bhr, ghz = bhz, ghn = bhn;
                #pragma unroll
                for (int k = 0; k < 64; ++k){
                    float4 w4 = WT4[2*4096 + lane*64 + k];
                    float hk = __shfl(h, k);
                    ghr = fmaf(w4.x, hk, ghr);
                    ghz = fmaf(w4.y, hk, ghz);
                    ghn = fmaf(w4.z, hk, ghn);
                }
                float r = sigm(g1r[tt] + ghr);
                float z = sigm(g1z[tt] + ghz);
                float n = tanhf(g1n[tt] + r*ghn);
                h = (1.f - z)*n + z*h;
                y_s[(b*TT + tt)*HH + lane] = h;
            }
        }
    }
    __syncthreads();
    float lam = fmaxf(lamp[0], 0.01f);
    if (tid < TT) out[BB*NC + tid] = expf(-lam*(float)tid);
    if (tid < BB*TT){
        int bb = tid >> 3, tt = tid & 7;
        float s = attn_b[0];
        const float* r = &y_s[(bb*TT+tt)*HH];
        for (int h = 0; h < HH; ++h) s += r[h]*attn_W[h];
        sc_s[bb*TT + tt] = s;
    }
    __syncthreads();
    if (tid < BB){
        float mx = -INFINITY;
        for (int tt = 0; tt < TT; ++tt) mx = fmaxf(mx, sc_s[tid*TT + tt]);
        float se = 0.f;
        for (int tt = 0; tt < TT; ++tt){
            float w = expf(sc_s[tid*TT + tt] - mx);
            at_s[tid*TT + tt] = w; se += w;
        }
        for (int tt = 0; tt < TT; ++tt){
            at_s[tid*TT + tt] /= se;
            out[BB*NC + TT + tid*TT + tt] = at_s[tid*TT + tt];
        }
    }
    __syncthreads();
    if (tid < BB*HH){
        int bb = tid >> 6, h = tid & 63;
        float a = 0.f;
        for (int tt = 0; tt < TT; ++tt) a += at_s[bb*TT + tt]*y_s[(bb*TT+tt)*HH + h];
        fin_s[bb*HH + h] = a;
    }
    __syncthreads();
    if (tid < BB*HH){
        int bb = tid >> 6, h = tid & 63;
        float a = b1[h];
        for (int k = 0; k < HH; ++k) a += fin_s[bb*HH + k]*W1[k*HH+h];
        z_s[bb*HH + h] = a;
    }
    __syncthreads();
    if (tid < BB){
        float mu = 0.f;
        for (int h = 0; h < HH; ++h) mu += z_s[tid*HH + h];
        mu *= (1.f/HH);
        float v = 0.f;
        for (int h = 0; h < HH; ++h){ float d = z_s[tid*HH + h]-mu; v += d*d; }
        v *= (1.f/HH);
        mu_s[tid] = mu; iv_s[tid] = 1.f/sqrtf(v + 1e-5f);
    }
    __syncthreads();
    if (tid < BB*HH){
        int bb = tid >> 6, h = tid & 63;
        float zn = (z_s[bb*HH + h]-mu_s[bb])*iv_s[bb]*ln_g[h] + ln_b[h];
        g_s[bb*HH + h] = 0.5f*zn*(1.f + erff(zn*0.70710678118654752f));
    }
    __syncthreads();
    if (tid < BB*NC){
        int bb = tid / NC, c = tid % NC;
        float a = b2[c];
        for (int k = 0; k < HH; ++k) a += g_s[bb*HH + k]*W2[k*NC+c];
        out[bb*NC + c] = a;
    }
}

extern "C" void kernel_launch(void* const* d_in, const int* in_sizes, int n_in,
                              void* d_out, int out_size, void* d_ws, size_t ws_size,
                              hipStream_t stream)
{
    const float* x_seq = (const float*)d_in[0];
    const float* sadj  = (const float*)d_in[1];
    const float* dynW  = (const float*)d_in[2];
    const float* lamp  = (const float*)d_in[3];
    const float* g1_Wl = (const float*)d_in[4];
    const float* g1_Wr = (const float*)d_in[5];
    const float* g1_att= (const float*)d_in[6];
    const float* g1_b  = (const float*)d_in[7];
    const float* g2_Wl = (const float*)d_in[8];
    const float* g2_Wr = (const float*)d_in[9];
    const float* g2_att= (const float*)d_in[10];
    const float* g2_b  = (const float*)d_in[11];
    const float* Wih0  = (const float*)d_in[12];
    const float* Whh0  = (const float*)d_in[13];
    const float* bih0  = (const float*)d_in[14];
    const float* bhh0  = (const float*)d_in[15];
    const float* Wih1  = (const float*)d_in[16];
    const float* Whh1  = (const float*)d_in[17];
    const float* bih1  = (const float*)d_in[18];
    const float* bhh1  = (const float*)d_in[19];
    const float* attnW = (const float*)d_in[20];
    const float* attnb = (const float*)d_in[21];
    const float* W1    = (const float*)d_in[22];
    const float* b1    = (const float*)d_in[23];
    const float* lng   = (const float*)d_in[24];
    const float* lnb   = (const float*)d_in[25];
    const float* W2    = (const float*)d_in[26];
    const float* b2    = (const float*)d_in[27];
    float* out = (float*)d_out;

    const int RWS = BB*TT*NN*HH;              // 524288
    uchar* M0 = (uchar*)d_ws;                 // 262144 B
    uchar* M1 = M0 + (size_t)NN*NN;           // 262144 B
    float* fb = (float*)(M1 + (size_t)NN*NN);
    float* AB   = fb;                         // 16
    float* ui   = AB   + 16;                  // 8192
    float* vj   = ui   + BB*TT*NN;            // 8192
    float* xl2  = vj   + BB*TT*NN;            // 524288
    float* xr2  = xl2  + RWS;                 // 524288
    float* hseq = xr2  + RWS;                 // 1024
    float* WT4  = hseq + BB*TT*HH;            // 49152 floats
    unsigned* done = (unsigned*)(WT4 + 3*4096*4);
    // total ~5 MB

    k_mask  <<<dim3(8,8,2), 256, 0, stream>>>(dynW, sadj, M0, M1, hseq, done,
                                              g1_att, g1_Wr, g1_Wl, AB,
                                              Whh0, Wih1, Whh1, (float4*)WT4);
    k_gat1f <<<dim3(NN/4, BB*TT), 256, 0, stream>>>(x_seq, M0, M1, g1_Wl, g1_Wr, g1_att, g1_b, AB,
                                                    g2_Wl, g2_Wr, g2_att, xl2, xr2, ui, vj);
    k_flash2<<<dim3(NN/8, BB*TT), 256, 0, stream>>>(xl2, xr2, M0, M1, g2_att, g2_b, ui, vj,
                                                    hseq, done,
                                                    Wih0, bih0, (const float4*)WT4, bhh0,
                                                    bih1, bhh1, lamp, attnW, attnb,
                                                    W1, b1, lng, lnb, W2, b2, out);
}

// Round 10
// 303.729 us; speedup vs baseline: 1.0875x; 1.0875x over previous
//
#include <hip/hip_runtime.h>
#include <math.h>

#define BB 2
#define TT 8
#define NN 512
#define HH 64
#define NC 10

typedef unsigned char uchar;

__device__ __forceinline__ float elu1(float v){ return v > 0.f ? v : expm1f(v); }
__device__ __forceinline__ float sigm(float v){ return 1.f/(1.f+expf(-v)); }

// ---------------- K0: masks; zero Z2/hseq/done; AB; GRU weight transposes ------
__global__ __launch_bounds__(256) void k_mask(
    const float* __restrict__ dW, const float* __restrict__ sadj,
    uchar* __restrict__ M0, uchar* __restrict__ M1,
    float* __restrict__ Z2, float* __restrict__ hseq, unsigned* __restrict__ done,
    const float* __restrict__ att1, const float* __restrict__ Wr1,
    const float* __restrict__ Wl1, float* __restrict__ AB,
    const float* __restrict__ Whh0, const float* __restrict__ Wih1,
    const float* __restrict__ Whh1, float4* __restrict__ WT4)
{
    __shared__ float tr[64][65];
    int bx = blockIdx.x, by = blockIdx.y;
    int tid = threadIdx.x;
    if (blockIdx.z == 1){
        int idx = (by*8 + bx)*256 + tid;
        if (idx < 3*4096){
            int m = idx >> 12, r = idx & 4095;
            int gg = r >> 6, k = r & 63;
            const float* W = (m == 0) ? Whh0 : (m == 1) ? Wih1 : Whh1;
            float4 o;
            o.x = W[k*192 + gg];
            o.y = W[k*192 + 64 + gg];
            o.z = W[k*192 + 128 + gg];
            o.w = 0.f;
            WT4[idx] = o;
        }
        return;
    }
    int i0 = by*64, j0 = bx*64;
    #pragma unroll
    for (int q = 0; q < 4; ++q){
        int r = (tid >> 4) + 16*q, c4 = tid & 15;
        float4 v = *(const float4*)&dW[(size_t)(j0+r)*NN + i0 + 4*c4];
        tr[r][4*c4+0] = v.x; tr[r][4*c4+1] = v.y;
        tr[r][4*c4+2] = v.z; tr[r][4*c4+3] = v.w;
    }
    __syncthreads();
    #pragma unroll
    for (int q = 0; q < 4; ++q){
        int row = (tid >> 4) + 16*q, c4 = tid & 15;
        int i = i0 + row, j = j0 + 4*c4;
        float4 d  = *(const float4*)&dW[(size_t)i*NN + j];
        float4 sa = *(const float4*)&sadj[(size_t)i*NN + j];
        uchar4 m0, m1;
        float dd0 = d.x + tr[4*c4+0][row];
        float dd1 = d.y + tr[4*c4+1][row];
        float dd2 = d.z + tr[4*c4+2][row];
        float dd3 = d.w + tr[4*c4+3][row];
        m0.x = (sa.x > 0.f) || (i == j+0);
        m0.y = (sa.y > 0.f) || (i == j+1);
        m0.z = (sa.z > 0.f) || (i == j+2);
        m0.w = (sa.w > 0.f) || (i == j+3);
        m1.x = m0.x || (dd0 > 0.f);
        m1.y = m0.y || (dd1 > 0.f);
        m1.z = m0.z || (dd2 > 0.f);
        m1.w = m0.w || (dd3 > 0.f);
        *(uchar4*)&M0[(size_t)i*NN + j] = m0;
        *(uchar4*)&M1[(size_t)i*NN + j] = m1;
    }
    int flat = (by*8 + bx)*256 + tid;
    if (flat < BB*TT*NN) Z2[flat] = 0.f;
    else if (flat < BB*TT*NN + BB*TT*HH) hseq[flat - BB*TT*NN] = 0.f;
    else if (flat == BB*TT*NN + BB*TT*HH) done[0] = 0u;
    if (bx == 0 && by == 0 && tid < 8){
        int h = tid & 3;
        const float* W = (tid < 4) ? Wr1 : Wl1;
        float s = 0.f;
        for (int c = 0; c < 16; ++c) s += att1[h*16+c]*W[h*16+c];
        AB[tid] = s;
    }
}

// ---------------- K1: GAT1 fused with lin2 (h1 stays in LDS) -------------------
__global__ __launch_bounds__(256) void k_gat1f(
    const float* __restrict__ x_seq, const uchar* __restrict__ M0,
    const uchar* __restrict__ M1,
    const float* __restrict__ Wl, const float* __restrict__ Wr,
    const float* __restrict__ att, const float* __restrict__ bias,
    const float* __restrict__ AB,
    const float* __restrict__ Wl2, const float* __restrict__ Wr2,
    const float* __restrict__ att2,
    float* __restrict__ xl2, float* __restrict__ xr2,
    float* __restrict__ ui, float* __restrict__ vj)
{
    __shared__ float x_s[NN];
    __shared__ float S_s[4][4];
    __shared__ float h_s[4][HH];
    __shared__ float Wl2_s[64*64];
    __shared__ float Wr2_s[64*64];
    int bt = blockIdx.y; int t = bt % TT;
    int i0 = blockIdx.x * 4;
    int tid = threadIdx.x;
    int il = tid >> 6, jl = tid & 63;
    int i = i0 + il;
    const uchar* M = t ? M1 : M0;
    ((float2*)x_s)[tid] = ((const float2*)(x_seq + bt*NN))[tid];
    #pragma unroll
    for (int q = 0; q < 4; ++q){
        int idx = q*256 + tid;
        ((float4*)Wl2_s)[idx] = ((const float4*)Wl2)[idx];
        ((float4*)Wr2_s)[idx] = ((const float4*)Wr2)[idx];
    }
    __syncthreads();
    float xi = x_s[i];
    const uchar* Mrow = M + (size_t)i*NN;
    float xj[8], msk[8];
    #pragma unroll
    for (int jj = 0; jj < 8; ++jj){
        int j = jj*64 + jl;
        xj[jj] = x_s[j];
        msk[jj] = Mrow[j] ? 1.f : 0.f;
    }
    float sw[4] = {0,0,0,0}, swx[4] = {0,0,0,0};
    for (int h = 0; h < 4; ++h){
        float acc[8] = {0,0,0,0,0,0,0,0};
        #pragma unroll
        for (int c = 0; c < 16; ++c){
            int hc = h*16 + c;
            float wl = Wl[hc];
            float q  = 0.4f * att[hc];
            float pr = xi * Wr[hc];
            #pragma unroll
            for (int jj = 0; jj < 8; ++jj){
                float s = fmaf(xj[jj], wl, pr);
                acc[jj] = fmaf(q, fabsf(s), acc[jj]);
            }
        }
        float lin = 0.6f * xi * AB[h];
        float al6 = 0.6f * AB[4+h];
        #pragma unroll
        for (int jj = 0; jj < 8; ++jj){
            float e = acc[jj] + fmaf(al6, xj[jj], lin);
            float w = msk[jj] * __expf(e);
            sw[h] += w;
            swx[h] = fmaf(w, xj[jj], swx[h]);
        }
    }
    #pragma unroll
    for (int off = 32; off; off >>= 1){
        #pragma unroll
        for (int h = 0; h < 4; ++h){
            sw[h]  += __shfl_down(sw[h],  off);
            swx[h] += __shfl_down(swx[h], off);
        }
    }
    if (jl == 0){
        #pragma unroll
        for (int h = 0; h < 4; ++h) S_s[il][h] = swx[h] / sw[h];
    }
    __syncthreads();
    {
        int hc = tid & 63, row = tid >> 6;
        float v = S_s[row][hc >> 4] * Wl[hc] + bias[hc];
        h_s[row][hc] = elu1(v);
    }
    __syncthreads();
    {
        int c = tid & 63, row = tid >> 6;
        float al = 0.f, ar = 0.f;
        #pragma unroll 8
        for (int k = 0; k < 64; ++k){
            float hv = h_s[row][k];
            al = fmaf(hv, Wl2_s[k*64 + c], al);
            ar = fmaf(hv, Wr2_s[k*64 + c], ar);
        }
        size_t ridx = (size_t)(bt*NN + i0 + row);
        xl2[ridx*HH + c] = al;
        xr2[ridx*HH + c] = ar;
        float a2 = att2[c];
        float pu = a2 * ar, pv = a2 * al;
        #pragma unroll
        for (int off = 32; off; off >>= 1){
            pu += __shfl_down(pu, off);
            pv += __shfl_down(pv, off);
        }
        if (c == 0){ ui[ridx] = pu; vj[ridx] = pv; }
    }
}

// ---------------- K2: GAT2 scores -> WgT[j][i] = exp(e) masked, Z atomics ------
// (R5-validated) block tile 64i x 64j, thread = 4i x 4j. grid (8, 8, 16).
__global__ __launch_bounds__(256) void k_e2(
    const float* __restrict__ xl2, const float* __restrict__ xr2,
    const uchar* __restrict__ M0, const uchar* __restrict__ M1,
    const float* __restrict__ att,
    const float* __restrict__ ui, const float* __restrict__ vj,
    float* __restrict__ WgT, float* __restrict__ Z2)
{
    __shared__ float xrT[64][68];
    __shared__ float xlT[64][68];
    int bt = blockIdx.z, t = bt % TT;
    int i0 = blockIdx.y*64, j0 = blockIdx.x*64;
    int base = bt*NN;
    int tid = threadIdx.x;
    const uchar* M = t ? M1 : M0;
    {
        int r = tid >> 2;
        #pragma unroll
        for (int q = 0; q < 4; ++q){
            int c4 = (tid & 3) + 4*q;
            float4 a = *(const float4*)&xr2[(size_t)(base+i0+r)*HH + 4*c4];
            float4 b = *(const float4*)&xl2[(size_t)(base+j0+r)*HH + 4*c4];
            xrT[4*c4+0][r] = a.x; xrT[4*c4+1][r] = a.y;
            xrT[4*c4+2][r] = a.z; xrT[4*c4+3][r] = a.w;
            xlT[4*c4+0][r] = b.x; xlT[4*c4+1][r] = b.y;
            xlT[4*c4+2][r] = b.z; xlT[4*c4+3][r] = b.w;
        }
    }
    int ti = tid >> 4, tj = tid & 15;
    int iL = ti*4, jL = tj*4;
    float4 u4 = *(const float4*)&ui[base+i0+iL];
    float4 v4 = *(const float4*)&vj[base+j0+jL];
    float uu[4] = {u4.x, u4.y, u4.z, u4.w};
    float vv[4] = {v4.x, v4.y, v4.z, v4.w};
    float acc[4][4];
    #pragma unroll
    for (int ii = 0; ii < 4; ++ii)
        #pragma unroll
        for (int jj = 0; jj < 4; ++jj)
            acc[ii][jj] = 0.6f*(uu[ii] + vv[jj]);
    __syncthreads();
    #pragma unroll 8
    for (int c = 0; c < 64; ++c){
        float qa = 0.4f * att[c];
        float4 a4 = *(const float4*)&xrT[c][iL];
        float4 b4 = *(const float4*)&xlT[c][jL];
        float a[4] = {a4.x, a4.y, a4.z, a4.w};
        float b[4] = {b4.x, b4.y, b4.z, b4.w};
        #pragma unroll
        for (int ii = 0; ii < 4; ++ii)
            #pragma unroll
            for (int jj = 0; jj < 4; ++jj)
                acc[ii][jj] = fmaf(qa, fabsf(a[ii] + b[jj]), acc[ii][jj]);
    }
    float w[4][4];
    #pragma unroll
    for (int ii = 0; ii < 4; ++ii){
        int i = i0 + iL + ii;
        uchar4 mr = *(const uchar4*)&M[(size_t)i*NN + j0 + jL];
        w[ii][0] = mr.x ? __expf(acc[ii][0]) : 0.f;
        w[ii][1] = mr.y ? __expf(acc[ii][1]) : 0.f;
        w[ii][2] = mr.z ? __expf(acc[ii][2]) : 0.f;
        w[ii][3] = mr.w ? __expf(acc[ii][3]) : 0.f;
    }
    #pragma unroll
    for (int jj = 0; jj < 4; ++jj){
        int j = j0 + jL + jj;
        float4 wv = { w[0][jj], w[1][jj], w[2][jj], w[3][jj] };
        *(float4*)&WgT[(size_t)(base+j)*NN + i0 + iL] = wv;
    }
    #pragma unroll
    for (int ii = 0; ii < 4; ++ii){
        float zi = w[ii][0] + w[ii][1] + w[ii][2] + w[ii][3];
        zi += __shfl_down(zi, 8);
        zi += __shfl_down(zi, 4);
        zi += __shfl_down(zi, 2);
        zi += __shfl_down(zi, 1);
        if (tj == 0) atomicAdd(&Z2[base + i0 + iL + ii], zi);
    }
}

// ---------------- K3: a2 (R5) + GRU/head tail in last block --------------------
// grid (32, 16); VGPR capped to 128 via launch_bounds min-waves=4.
__global__ __launch_bounds__(256, 4) void k_a2t(
    const float* __restrict__ WgT, const float* __restrict__ xl2,
    const float* __restrict__ Z2, const float* __restrict__ bias,
    float* __restrict__ hseq, unsigned* __restrict__ done,
    const float* __restrict__ Wih0, const float* __restrict__ bih0,
    const float4* __restrict__ WT4, const float* __restrict__ bhh0,
    const float* __restrict__ bih1, const float* __restrict__ bhh1,
    const float* __restrict__ lamp, const float* __restrict__ attn_W,
    const float* __restrict__ attn_b, const float* __restrict__ W1,
    const float* __restrict__ b1, const float* __restrict__ ln_g,
    const float* __restrict__ ln_b, const float* __restrict__ W2,
    const float* __restrict__ b2, float* __restrict__ out)
{
    __shared__ __align__(16) float S[5696];
    __shared__ unsigned isLast;
    float* a_s  = S;            // [64][20]  1280
    float* x_s  = S + 1280;     // [64][68]  4352
    float* msum = S + 5632;     // 64
    int bt = blockIdx.y;
    int i0 = blockIdx.x * 16;
    int base = bt * NN;
    int tid = threadIdx.x;
    int tg = tid >> 4, tc = tid & 15;
    if (tid < 64) msum[tid] = 0.f;
    float4 acc = {0,0,0,0};
    for (int jc = 0; jc < 8; ++jc){
        int j0 = jc*64;
        {
            int row = tid >> 2, c4 = tid & 3;
            *(float4*)&a_s[row*20 + 4*c4] = *(const float4*)&WgT[(size_t)(base+j0+row)*NN + i0 + 4*c4];
        }
        #pragma unroll
        for (int q = 0; q < 4; ++q){
            int idx = q*256 + tid; int row = idx >> 4, c4 = idx & 15;
            *(float4*)&x_s[row*68 + 4*c4] = *(const float4*)&xl2[(size_t)(base+j0+row)*HH + 4*c4];
        }
        __syncthreads();
        #pragma unroll 8
        for (int j = 0; j < 64; ++j){
            float a = a_s[j*20 + tg];
            float4 xv = *(const float4*)&x_s[j*68 + 4*tc];
            acc.x = fmaf(a, xv.x, acc.x);
            acc.y = fmaf(a, xv.y, acc.y);
            acc.z = fmaf(a, xv.z, acc.z);
            acc.w = fmaf(a, xv.w, acc.w);
        }
        __syncthreads();
    }
    float rz = 1.f / Z2[base + i0 + tg];
    float4 b4 = ((const float4*)bias)[tc];
    float4 h;
    h.x = elu1(acc.x*rz + b4.x);
    h.y = elu1(acc.y*rz + b4.y);
    h.z = elu1(acc.z*rz + b4.z);
    h.w = elu1(acc.w*rz + b4.w);
    atomicAdd(&msum[4*tc+0], h.x);
    atomicAdd(&msum[4*tc+1], h.y);
    atomicAdd(&msum[4*tc+2], h.z);
    atomicAdd(&msum[4*tc+3], h.w);
    __syncthreads();
    if (tid < 64) atomicAdd(&hseq[bt*HH + tid], msum[tid]*(1.f/(float)NN));
    // ---- last-block detection (R9-validated pattern) ----
    if (tid == 0){
        __threadfence();
        unsigned old = __hip_atomic_fetch_add(done, 1u, __ATOMIC_ACQ_REL, __HIP_MEMORY_SCOPE_AGENT);
        isLast = (old == 32u*16u - 1u) ? 1u : 0u;
        if (isLast) __threadfence();
    }
    __syncthreads();
    if (!isLast) return;
    // ================= tail: hseq -> gi0 -> serial GRU x2 -> head ==============
    float* hs   = S;              // 1024
    float* gi_s = S + 1024;       // 3072
    float* y_s  = S + 4096;       // 1024
    float* sc_s = S + 5120;       // 16
    float* at_s = S + 5136;       // 16
    float* fin_s= S + 5152;       // 128
    float* z_s  = S + 5280;       // 128
    float* g_s  = S + 5408;       // 128
    float* mu_s = S + 5536;       // 2
    float* iv_s = S + 5538;       // 2
    __syncthreads();
    for (int o = tid; o < BB*TT*HH; o += 256)
        hs[o] = __hip_atomic_load(&hseq[o], __ATOMIC_RELAXED, __HIP_MEMORY_SCOPE_AGENT);
    __syncthreads();
    for (int o = tid; o < BB*TT*192; o += 256){
        int b = o / 192, g = o % 192;
        float a = bih0[g];
        #pragma unroll 8
        for (int k = 0; k < HH; ++k)
            a = fmaf(hs[b*HH + k], Wih0[k*192 + g], a);
        gi_s[o] = a;
    }
    __syncthreads();
    int wave = tid >> 6, lane = tid & 63;
    if (wave < 2){
        int b = wave;
        float y[TT], g1r[TT], g1z[TT], g1n[TT];
        {
            float bhr = bhh0[lane], bhz = bhh0[64+lane], bhn = bhh0[128+lane];
            float hh = 0.f;
            for (int tt = 0; tt < TT; ++tt){
                float ghr = bhr, ghz = bhz, ghn = bhn;
                #pragma unroll 8
                for (int k = 0; k < 64; ++k){
                    float4 w4 = WT4[lane*64 + k];
                    float hk = __shfl(hh, k);
                    ghr = fmaf(w4.x, hk, ghr);
                    ghz = fmaf(w4.y, hk, ghz);
                    ghn = fmaf(w4.z, hk, ghn);
                }
                const float* gi = &gi_s[(b*TT + tt)*192];
                float r = sigm(gi[lane] + ghr);
                float z = sigm(gi[64+lane] + ghz);
                float n = tanhf(gi[128+lane] + r*ghn);
                hh = (1.f - z)*n + z*hh;
                y[tt] = hh;
            }
        }
        {
            float bi1r = bih1[lane], bi1z = bih1[64+lane], bi1n = bih1[128+lane];
            #pragma unroll
            for (int tt = 0; tt < TT; ++tt){ g1r[tt] = bi1r; g1z[tt] = bi1z; g1n[tt] = bi1n; }
            #pragma unroll 4
            for (int k = 0; k < 64; ++k){
                float4 w4 = WT4[4096 + lane*64 + k];
                #pragma unroll
                for (int tt = 0; tt < TT; ++tt){
                    float yk = __shfl(y[tt], k);
                    g1r[tt] = fmaf(w4.x, yk, g1r[tt]);
                    g1z[tt] = fmaf(w4.y, yk, g1z[tt]);
                    g1n[tt] = fmaf(w4.z, yk, g1n[tt]);
                }
            }
        }
        {
            float bhr = bhh1[lane], bhz = bhh1[64+lane], bhn = bhh1[128+lane];
            float hh = 0.f;
            for (int tt = 0; tt < TT; ++tt){
                float ghr = bhr, ghz = bhz, ghn = bhn;
                #pragma unroll 8
                for (int k = 0; k < 64; ++k){
                    float4 w4 = WT4[2*4096 + lane*64 + k];
                    float hk = __shfl(hh, k);
                    ghr = fmaf(w4.x, hk, ghr);
                    ghz = fmaf(w4.y, hk, ghz);
                    ghn = fmaf(w4.z, hk, ghn);
                }
                float r = sigm(g1r[tt] + ghr);
                float z = sigm(g1z[tt] + ghz);
                float n = tanhf(g1n[tt] + r*ghn);
                hh = (1.f - z)*n + z*hh;
                y_s[(b*TT + tt)*HH + lane] = hh;
            }
        }
    }
    __syncthreads();
    float lam = fmaxf(lamp[0], 0.01f);
    if (tid < TT) out[BB*NC + tid] = expf(-lam*(float)tid);
    if (tid < BB*TT){
        int bb = tid >> 3, tt = tid & 7;
        float s = attn_b[0];
        const float* r = &y_s[(bb*TT+tt)*HH];
        for (int hh = 0; hh < HH; ++hh) s += r[hh]*attn_W[hh];
        sc_s[bb*TT + tt] = s;
    }
    __syncthreads();
    if (tid < BB){
        float mx = -INFINITY;
        for (int tt = 0; tt < TT; ++tt) mx = fmaxf(mx, sc_s[tid*TT + tt]);
        float se = 0.f;
        for (int tt = 0; tt < TT; ++tt){
            float w = expf(sc_s[tid*TT + tt] - mx);
            at_s[tid*TT + tt] = w; se += w;
        }
        for (int tt = 0; tt < TT; ++tt){
            at_s[tid*TT + tt] /= se;
            out[BB*NC + TT + tid*TT + tt] = at_s[tid*TT + tt];
        }
    }
    __syncthreads();
    if (tid < BB*HH){
        int bb = tid >> 6, hh = tid & 63;
        float a = 0.f;
        for (int tt = 0; tt < TT; ++tt) a += at_s[bb*TT + tt]*y_s[(bb*TT+tt)*HH + hh];
        fin_s[bb*HH + hh] = a;
    }
    __syncthreads();
    if (tid < BB*HH){
        int bb = tid >> 6, hh = tid & 63;
        float a = b1[hh];
        for (int k = 0; k < HH; ++k) a += fin_s[bb*HH + k]*W1[k*HH+hh];
        z_s[bb*HH + hh] = a;
    }
    __syncthreads();
    if (tid < BB){
        float mu = 0.f;
        for (int hh = 0; hh < HH; ++hh) mu += z_s[tid*HH + hh];
        mu *= (1.f/HH);
        float v = 0.f;
        for (int hh = 0; hh < HH; ++hh){ float d = z_s[tid*HH + hh]-mu; v += d*d; }
        v *= (1.f/HH);
        mu_s[tid] = mu; iv_s[tid] = 1.f/sqrtf(v + 1e-5f);
    }
    __syncthreads();
    if (tid < BB*HH){
        int bb = tid >> 6, hh = tid & 63;
        float zn = (z_s[bb*HH + hh]-mu_s[bb])*iv_s[bb]*ln_g[hh] + ln_b[hh];
        g_s[bb*HH + hh] = 0.5f*zn*(1.f + erff(zn*0.70710678118654752f));
    }
    __syncthreads();
    if (tid < BB*NC){
        int bb = tid / NC, c = tid % NC;
        float a = b2[c];
        for (int k = 0; k < HH; ++k) a += g_s[bb*HH + k]*W2[k*NC+c];
        out[bb*NC + c] = a;
    }
}

extern "C" void kernel_launch(void* const* d_in, const int* in_sizes, int n_in,
                              void* d_out, int out_size, void* d_ws, size_t ws_size,
                              hipStream_t stream)
{
    const float* x_seq = (const float*)d_in[0];
    const float* sadj  = (const float*)d_in[1];
    const float* dynW  = (const float*)d_in[2];
    const float* lamp  = (const float*)d_in[3];
    const float* g1_Wl = (const float*)d_in[4];
    const float* g1_Wr = (const float*)d_in[5];
    const float* g1_att= (const float*)d_in[6];
    const float* g1_b  = (const float*)d_in[7];
    const float* g2_Wl = (const float*)d_in[8];
    const float* g2_Wr = (const float*)d_in[9];
    const float* g2_att= (const float*)d_in[10];
    const float* g2_b  = (const float*)d_in[11];
    const float* Wih0  = (const float*)d_in[12];
    const float* Whh0  = (const float*)d_in[13];
    const float* bih0  = (const float*)d_in[14];
    const float* bhh0  = (const float*)d_in[15];
    const float* Wih1  = (const float*)d_in[16];
    const float* Whh1  = (const float*)d_in[17];
    const float* bih1  = (const float*)d_in[18];
    const float* bhh1  = (const float*)d_in[19];
    const float* attnW = (const float*)d_in[20];
    const float* attnb = (const float*)d_in[21];
    const float* W1    = (const float*)d_in[22];
    const float* b1    = (const float*)d_in[23];
    const float* lng   = (const float*)d_in[24];
    const float* lnb   = (const float*)d_in[25];
    const float* W2    = (const float*)d_in[26];
    const float* b2    = (const float*)d_in[27];
    float* out = (float*)d_out;

    const int RWS = BB*TT*NN*HH;              // 524288
    uchar* M0 = (uchar*)d_ws;                 // 262144 B
    uchar* M1 = M0 + (size_t)NN*NN;           // 262144 B
    float* fb = (float*)(M1 + (size_t)NN*NN);
    float* Z2   = fb;                         // 8192
    float* AB   = Z2   + BB*TT*NN;            // 16
    float* ui   = AB   + 16;                  // 8192
    float* vj   = ui   + BB*TT*NN;            // 8192
    float* xl2  = vj   + BB*TT*NN;            // 524288
    float* xr2  = xl2  + RWS;                 // 524288
    float* WgT  = xr2  + RWS;                 // 4194304
    float* hseq = WgT  + (size_t)BB*TT*NN*NN; // 1024
    float* WT4  = hseq + BB*TT*HH;            // 49152 floats
    unsigned* done = (unsigned*)(WT4 + 3*4096*4);
    // total ~21.6 MB

    k_mask <<<dim3(8,8,2), 256, 0, stream>>>(dynW, sadj, M0, M1, Z2, hseq, done,
                                             g1_att, g1_Wr, g1_Wl, AB,
                                             Whh0, Wih1, Whh1, (float4*)WT4);
    k_gat1f<<<dim3(NN/4, BB*TT), 256, 0, stream>>>(x_seq, M0, M1, g1_Wl, g1_Wr, g1_att, g1_b, AB,
                                                   g2_Wl, g2_Wr, g2_att, xl2, xr2, ui, vj);
    k_e2   <<<dim3(NN/64, NN/64, BB*TT), 256, 0, stream>>>(xl2, xr2, M0, M1, g2_att, ui, vj, WgT, Z2);
    k_a2t  <<<dim3(NN/16, BB*TT), 256, 0, stream>>>(WgT, xl2, Z2, g2_b, hseq, done,
                                                    Wih0, bih0, (const float4*)WT4, bhh0,
                                                    bih1, bhh1, lamp, attnW, attnb,
                                                    W1, b1, lng, lnb, W2, b2, out);
}